// Round 1
// baseline (310.636 us; speedup 1.0000x reference)
//
#include <hip/hip_runtime.h>
#include <hip/hip_bf16.h>

typedef __attribute__((ext_vector_type(8))) short short8;   // 8 bf16 = 4 VGPR (MFMA A/B frag)
typedef __attribute__((ext_vector_type(4))) float f32x4;    // MFMA C/D frag

__device__ __forceinline__ unsigned short f2bf(float f) {
    union { __hip_bfloat16 h; unsigned short u; } cv;
    cv.h = __float2bfloat16(f);   // RNE
    return cv.u;
}

// jax.nn.gelu(approximate=True): 0.5x(1+tanh(sqrt(2/pi)(x+0.044715x^3))) == x*e/(e+1), e=exp(2*inner)
__device__ __forceinline__ float gelu_t(float x) {
    float e = __expf(1.5957691216057308f * x * __builtin_fmaf(0.044715f, x * x, 1.0f));
    return x * (e / (e + 1.0f));
}

__device__ __forceinline__ void gload_lds16(const void* g, void* l) {
    __builtin_amdgcn_global_load_lds((const __attribute__((address_space(1))) unsigned int*)g,
                                     (__attribute__((address_space(3))) unsigned int*)l, 16, 0, 0);
}

// ---------------------------------------------------------------------------
// Transpose + f32->bf16 + pre-swizzle:  out[n][k] = in[k][n]
// Swizzle: within each 64B k-slice of a row, byte ^= ((n&3)<<4)  (matches BK=32 tiles)
// ---------------------------------------------------------------------------
__global__ __launch_bounds__(256) void transpose_swz(const float* __restrict__ in,
                                                     unsigned short* __restrict__ out,
                                                     int K, int N) {
    __shared__ float tile[64][65];
    int k0 = blockIdx.x * 64, n0 = blockIdx.y * 64;
    int t = threadIdx.x;
    int c = t & 63, r0 = t >> 6;
#pragma unroll
    for (int i = 0; i < 16; i++) {
        int r = r0 + i * 4;
        tile[r][c] = in[(size_t)(k0 + r) * N + n0 + c];
    }
    __syncthreads();
    int kk = t & 15;       // 4 k's (8 bytes) per thread
    int nl0 = t >> 4;      // 16 n-rows per iter
#pragma unroll
    for (int i = 0; i < 4; i++) {
        int nl = nl0 + i * 16;
        int n  = n0 + nl;
        unsigned short b0 = f2bf(tile[kk * 4 + 0][nl]);
        unsigned short b1 = f2bf(tile[kk * 4 + 1][nl]);
        unsigned short b2 = f2bf(tile[kk * 4 + 2][nl]);
        unsigned short b3 = f2bf(tile[kk * 4 + 3][nl]);
        uint2 v;
        v.x = (unsigned)b0 | ((unsigned)b1 << 16);
        v.y = (unsigned)b2 | ((unsigned)b3 << 16);
        int byte_in_chunk = kk * 8;                       // 0..127 (two 64B slices)
        int slice = byte_in_chunk & ~63;
        int off   = (byte_in_chunk & 63) ^ ((n & 3) << 4);
        size_t obyte = (size_t)n * (K * 2) + (size_t)k0 * 2 + slice + off;
        *(uint2*)((char*)out + obyte) = v;
    }
}

// ---------------------------------------------------------------------------
// Small GEMM: C[M][512] = A[M][512] @ Bt^T (+bias), A f32 -> bf16 on the fly.
// Bt: pre-swizzled bf16 [512][512]. BM=128 BN=128 BK=32, 256 thr, 4 waves 2x2.
// ---------------------------------------------------------------------------
__global__ __launch_bounds__(256, 2) void gemm_small(const float* __restrict__ A,
                                                     const unsigned short* __restrict__ Bt,
                                                     const float* __restrict__ bias,
                                                     float* __restrict__ C) {
    __shared__ alignas(16) unsigned short As[128 * 32];
    __shared__ alignas(16) unsigned short Bs[128 * 32];
    int t = threadIdx.x;
    size_t m0 = (size_t)blockIdx.x * 128;
    int n0 = blockIdx.y * 128;
    int lane = t & 63, w = t >> 6;
    int wm = w >> 1, wn = w & 1;
    int rA = t >> 3, cg = t & 7;  // staging: 8 thr/row (float4 each), 32 rows/pass
    f32x4 acc[4][4] = {};

    for (int kt = 0; kt < 16; ++kt) {
        int k0 = kt * 32;
        __syncthreads();
        // stage A (f32 -> bf16, swizzled)
#pragma unroll
        for (int p = 0; p < 4; p++) {
            int r = rA + p * 32;
            f32x4 v = *(const f32x4*)&A[(m0 + r) * 512 + k0 + cg * 4];
            uint2 pk;
            pk.x = (unsigned)f2bf(v.x) | ((unsigned)f2bf(v.y) << 16);
            pk.y = (unsigned)f2bf(v.z) | ((unsigned)f2bf(v.w) << 16);
            int off = (cg * 8) ^ ((r & 3) << 4);
            *(uint2*)((char*)As + r * 64 + off) = pk;
        }
        // stage B: 8KB via global_load_lds (pre-swizzled source, linear LDS dest)
#pragma unroll
        for (int j = 0; j < 2; j++) {
            int ibyte = w * 1024 + j * 4096;           // wave-uniform LDS base
            int lb = ibyte + lane * 16;
            int row = lb >> 6, colb = lb & 63;
            const char* src = (const char*)Bt + (size_t)(n0 + row) * 1024 + k0 * 2 + colb;
            gload_lds16(src, (char*)Bs + ibyte);
        }
        __syncthreads();
        short8 af[4], bf[4];
#pragma unroll
        for (int mi = 0; mi < 4; mi++) {
            int r = wm * 64 + mi * 16 + (lane & 15);
            int off = ((lane >> 4) * 16) ^ ((r & 3) << 4);
            af[mi] = *(const short8*)((const char*)As + r * 64 + off);
        }
#pragma unroll
        for (int ni = 0; ni < 4; ni++) {
            int n = wn * 64 + ni * 16 + (lane & 15);
            int off = ((lane >> 4) * 16) ^ ((n & 3) << 4);
            bf[ni] = *(const short8*)((const char*)Bs + n * 64 + off);
        }
#pragma unroll
        for (int mi = 0; mi < 4; mi++)
#pragma unroll
            for (int ni = 0; ni < 4; ni++)
                acc[mi][ni] = __builtin_amdgcn_mfma_f32_16x16x32_bf16(af[mi], bf[ni], acc[mi][ni], 0, 0, 0);
    }
    // epilogue: C/D layout col=lane&15, row=(lane>>4)*4+q (m89-verified)
#pragma unroll
    for (int mi = 0; mi < 4; mi++) {
        int row = wm * 64 + mi * 16 + ((lane >> 4) << 2);
#pragma unroll
        for (int ni = 0; ni < 4; ni++) {
            int col = n0 + wn * 64 + ni * 16 + (lane & 15);
            float bv = bias ? bias[col] : 0.0f;
#pragma unroll
            for (int q = 0; q < 4; q++)
                C[(m0 + row + q) * 512 + col] = acc[mi][ni][q] + bv;
        }
    }
}

// ---------------------------------------------------------------------------
// Big fused GEMM: out[m][v] = gelu(he[bt(m)] + hd[bu(m)]) @ W2,  m in [0,98304)
// BM=128 BN=512 BK=32, 512 thr (8 waves 2m x 4n, 64x128/wave), 16 K-steps.
// ---------------------------------------------------------------------------
__global__ __launch_bounds__(512, 2) void joint_big(const float* __restrict__ he,
                                                    const float* __restrict__ hd,
                                                    const unsigned short* __restrict__ W2t,
                                                    float* __restrict__ out) {
    __shared__ alignas(16) unsigned short As[128 * 32];   //  8 KB
    __shared__ alignas(16) unsigned short Bs[512 * 32];   // 32 KB
    int t = threadIdx.x;
    int mt = blockIdx.x;           // 0..767
    int n0 = blockIdx.y * 512;     // 0 or 512
    size_t m0 = (size_t)mt * 128;
    int lane = t & 63, w = t >> 6;
    int wm = w >> 2, wn = w & 3;   // 2m x 4n

    // A-generation assignment (fixed per thread): row r=t>>2, k-chunk cg=t&3 (8 cols)
    int rA = t >> 2, cg = t & 3;
    int mrow = (int)m0 + rA;
    int tIdx = mrow / 96;                 // b*256 + t  (0..1023)
    int u    = mrow - tIdx * 96;
    int b    = tIdx >> 8;
    const float* heRow = he + (size_t)tIdx * 512 + cg * 8;
    const float* hdRow = hd + (size_t)(b * 96 + u) * 512 + cg * 8;
    int aoff = rA * 64 + ((cg * 16) ^ ((rA & 3) << 4));

    f32x4 acc[4][8] = {};

    for (int kt = 0; kt < 16; ++kt) {
        int k0 = kt * 32;
        // ---- A-gen compute BEFORE barrier (no LDS dep -> overlaps prev MFMA drain)
        f32x4 e0 = *(const f32x4*)(heRow + k0);
        f32x4 d0 = *(const f32x4*)(hdRow + k0);
        f32x4 e1 = *(const f32x4*)(heRow + k0 + 4);
        f32x4 d1 = *(const f32x4*)(hdRow + k0 + 4);
        float h0 = gelu_t(e0.x + d0.x), h1 = gelu_t(e0.y + d0.y);
        float h2 = gelu_t(e0.z + d0.z), h3 = gelu_t(e0.w + d0.w);
        float h4 = gelu_t(e1.x + d1.x), h5 = gelu_t(e1.y + d1.y);
        float h6 = gelu_t(e1.z + d1.z), h7 = gelu_t(e1.w + d1.w);
        uint4 pk;
        pk.x = (unsigned)f2bf(h0) | ((unsigned)f2bf(h1) << 16);
        pk.y = (unsigned)f2bf(h2) | ((unsigned)f2bf(h3) << 16);
        pk.z = (unsigned)f2bf(h4) | ((unsigned)f2bf(h5) << 16);
        pk.w = (unsigned)f2bf(h6) | ((unsigned)f2bf(h7) << 16);
        __syncthreads();                       // prev iter's frag reads done
        *(uint4*)((char*)As + aoff) = pk;
        // ---- stage B: 32 KB, 4 x 1KB per wave, pre-swizzled source
#pragma unroll
        for (int j = 0; j < 4; j++) {
            int ibyte = w * 4096 + j * 1024;   // wave-uniform LDS base
            int lb = ibyte + lane * 16;
            int row = lb >> 6, colb = lb & 63;
            const char* src = (const char*)W2t + (size_t)(n0 + row) * 1024 + k0 * 2 + colb;
            gload_lds16(src, (char*)Bs + ibyte);
        }
        __syncthreads();                       // vmcnt+lgkm drained by compiler
        // ---- fragments + MFMA
        short8 af[4], bfr[8];
#pragma unroll
        for (int mi = 0; mi < 4; mi++) {
            int r = wm * 64 + mi * 16 + (lane & 15);
            int off = ((lane >> 4) * 16) ^ ((r & 3) << 4);
            af[mi] = *(const short8*)((const char*)As + r * 64 + off);
        }
#pragma unroll
        for (int ni = 0; ni < 8; ni++) {
            int n = wn * 128 + ni * 16 + (lane & 15);
            int off = ((lane >> 4) * 16) ^ ((n & 3) << 4);
            bfr[ni] = *(const short8*)((const char*)Bs + n * 64 + off);
        }
#pragma unroll
        for (int mi = 0; mi < 4; mi++)
#pragma unroll
            for (int ni = 0; ni < 8; ni++)
                acc[mi][ni] = __builtin_amdgcn_mfma_f32_16x16x32_bf16(af[mi], bfr[ni], acc[mi][ni], 0, 0, 0);
    }
    // ---- epilogue: f32 stores, 16 lanes cover one 64B line per row
#pragma unroll
    for (int mi = 0; mi < 4; mi++) {
        int row = wm * 64 + mi * 16 + ((lane >> 4) << 2);
        size_t mg = m0 + row;
#pragma unroll
        for (int ni = 0; ni < 8; ni++) {
            int col = n0 + wn * 128 + ni * 16 + (lane & 15);
            float* o = out + mg * 1024 + col;
            o[0]        = acc[mi][ni][0];
            o[1024]     = acc[mi][ni][1];
            o[2048]     = acc[mi][ni][2];
            o[3072]     = acc[mi][ni][3];
        }
    }
}

extern "C" void kernel_launch(void* const* d_in, const int* in_sizes, int n_in,
                              void* d_out, int out_size, void* d_ws, size_t ws_size,
                              hipStream_t stream) {
    const float* enc = (const float*)d_in[0];   // (4,256,512)
    const float* dec = (const float*)d_in[1];   // (4,96,512)
    const float* W1  = (const float*)d_in[2];   // (1024,512)
    const float* b1  = (const float*)d_in[3];   // (512,)
    const float* W2  = (const float*)d_in[4];   // (512,1024)
    float* out = (float*)d_out;                 // (4,256,96,1024) f32

    char* ws = (char*)d_ws;
    float* he = (float*)(ws);                               // 1024x512 f32 (bias folded)
    float* hd = (float*)(ws + 2097152);                     //  384x512 f32
    unsigned short* Wet = (unsigned short*)(ws + 2883584);  // 512x512 bf16 swz
    unsigned short* Wdt = (unsigned short*)(ws + 3407872);  // 512x512 bf16 swz
    unsigned short* W2t = (unsigned short*)(ws + 3932160);  // 1024x512 bf16 swz

    transpose_swz<<<dim3(8, 8),  256, 0, stream>>>(W1,             Wet, 512, 512);
    transpose_swz<<<dim3(8, 8),  256, 0, stream>>>(W1 + 512 * 512, Wdt, 512, 512);
    transpose_swz<<<dim3(8, 16), 256, 0, stream>>>(W2,             W2t, 512, 1024);

    gemm_small<<<dim3(8, 4), 256, 0, stream>>>(enc, Wet, b1,      he);   // he + b1
    gemm_small<<<dim3(3, 4), 256, 0, stream>>>(dec, Wdt, nullptr, hd);   // hd

    joint_big<<<dim3(768, 2), 512, 0, stream>>>(he, hd, W2t, out);
}

// Round 2
// 271.423 us; speedup vs baseline: 1.1445x; 1.1445x over previous
//
#include <hip/hip_runtime.h>
#include <hip/hip_bf16.h>
#include <initializer_list>

typedef __attribute__((ext_vector_type(8))) short short8;   // 8 bf16 = 4 VGPR (MFMA A/B frag)
typedef __attribute__((ext_vector_type(4))) float f32x4;    // MFMA C/D frag

__device__ __forceinline__ unsigned short f2bf(float f) {
    union { __hip_bfloat16 h; unsigned short u; } cv;
    cv.h = __float2bfloat16(f);   // RNE
    return cv.u;
}

// jax.nn.gelu(approximate=True): 0.5x(1+tanh(sqrt(2/pi)(x+0.044715x^3))) == x*e/(e+1), e=exp(2*inner)
__device__ __forceinline__ float gelu_t(float x) {
    float e = __expf(1.5957691216057308f * x * __builtin_fmaf(0.044715f, x * x, 1.0f));
    return x * (e / (e + 1.0f));
}

__device__ __forceinline__ void gload_lds16(const void* g, void* l) {
    __builtin_amdgcn_global_load_lds((const __attribute__((address_space(1))) unsigned int*)g,
                                     (__attribute__((address_space(3))) unsigned int*)l, 16, 0, 0);
}

// ---------------------------------------------------------------------------
// OLD-layout transpose (BK=32 / 64B slices, XOR (n&3)<<4) — for gemm_small's
// Wet/Wdt and for the fallback joint_big path.  (verified R1)
// ---------------------------------------------------------------------------
__global__ __launch_bounds__(256) void transpose_swz(const float* __restrict__ in,
                                                     unsigned short* __restrict__ out,
                                                     int K, int N) {
    __shared__ float tile[64][65];
    int k0 = blockIdx.x * 64, n0 = blockIdx.y * 64;
    int t = threadIdx.x;
    int c = t & 63, r0 = t >> 6;
#pragma unroll
    for (int i = 0; i < 16; i++) {
        int r = r0 + i * 4;
        tile[r][c] = in[(size_t)(k0 + r) * N + n0 + c];
    }
    __syncthreads();
    int kk = t & 15;
    int nl0 = t >> 4;
#pragma unroll
    for (int i = 0; i < 4; i++) {
        int nl = nl0 + i * 16;
        int n  = n0 + nl;
        unsigned short b0 = f2bf(tile[kk * 4 + 0][nl]);
        unsigned short b1 = f2bf(tile[kk * 4 + 1][nl]);
        unsigned short b2 = f2bf(tile[kk * 4 + 2][nl]);
        unsigned short b3 = f2bf(tile[kk * 4 + 3][nl]);
        uint2 v;
        v.x = (unsigned)b0 | ((unsigned)b1 << 16);
        v.y = (unsigned)b2 | ((unsigned)b3 << 16);
        int byte_in_chunk = kk * 8;
        int slice = byte_in_chunk & ~63;
        int off   = (byte_in_chunk & 63) ^ ((n & 3) << 4);
        size_t obyte = (size_t)n * (K * 2) + (size_t)k0 * 2 + slice + off;
        *(uint2*)((char*)out + obyte) = v;
    }
}

// ---------------------------------------------------------------------------
// NEW-layout transpose (BK=64 / 128B slices, XOR (n&7)<<4) — W2 for joint_gemm.
// out byte = n*(2K) + (k>>6)*128 + ((kslice_byte) ^ ((n&7)<<4))
// ---------------------------------------------------------------------------
__global__ __launch_bounds__(256) void transpose_swz64(const float* __restrict__ in,
                                                       unsigned short* __restrict__ out,
                                                       int K, int N) {
    __shared__ float tile[64][65];
    int k0 = blockIdx.x * 64, n0 = blockIdx.y * 64;
    int t = threadIdx.x;
    int c = t & 63, r0 = t >> 6;
#pragma unroll
    for (int i = 0; i < 16; i++) {
        int r = r0 + i * 4;
        tile[r][c] = in[(size_t)(k0 + r) * N + n0 + c];
    }
    __syncthreads();
    int kk = t & 15;       // 4 k's = 8 bytes per thread
    int nl0 = t >> 4;
#pragma unroll
    for (int i = 0; i < 4; i++) {
        int nl = nl0 + i * 16;
        int n  = n0 + nl;
        unsigned short b0 = f2bf(tile[kk * 4 + 0][nl]);
        unsigned short b1 = f2bf(tile[kk * 4 + 1][nl]);
        unsigned short b2 = f2bf(tile[kk * 4 + 2][nl]);
        unsigned short b3 = f2bf(tile[kk * 4 + 3][nl]);
        uint2 v;
        v.x = (unsigned)b0 | ((unsigned)b1 << 16);
        v.y = (unsigned)b2 | ((unsigned)b3 << 16);
        size_t obyte = (size_t)n * (K * 2) + (size_t)(k0 >> 6) * 128 + ((kk * 8) ^ ((n & 7) << 4));
        *(uint2*)((char*)out + obyte) = v;
    }
}

// ---------------------------------------------------------------------------
// Small GEMM: C[M][512] = A[M][512] @ Bt^T (+bias). (verified R1, unchanged)
// ---------------------------------------------------------------------------
__global__ __launch_bounds__(256, 2) void gemm_small(const float* __restrict__ A,
                                                     const unsigned short* __restrict__ Bt,
                                                     const float* __restrict__ bias,
                                                     float* __restrict__ C) {
    __shared__ alignas(16) unsigned short As[128 * 32];
    __shared__ alignas(16) unsigned short Bs[128 * 32];
    int t = threadIdx.x;
    size_t m0 = (size_t)blockIdx.x * 128;
    int n0 = blockIdx.y * 128;
    int lane = t & 63, w = t >> 6;
    int wm = w >> 1, wn = w & 1;
    int rA = t >> 3, cg = t & 7;
    f32x4 acc[4][4] = {};

    for (int kt = 0; kt < 16; ++kt) {
        int k0 = kt * 32;
        __syncthreads();
#pragma unroll
        for (int p = 0; p < 4; p++) {
            int r = rA + p * 32;
            f32x4 v = *(const f32x4*)&A[(m0 + r) * 512 + k0 + cg * 4];
            uint2 pk;
            pk.x = (unsigned)f2bf(v.x) | ((unsigned)f2bf(v.y) << 16);
            pk.y = (unsigned)f2bf(v.z) | ((unsigned)f2bf(v.w) << 16);
            int off = (cg * 8) ^ ((r & 3) << 4);
            *(uint2*)((char*)As + r * 64 + off) = pk;
        }
#pragma unroll
        for (int j = 0; j < 2; j++) {
            int ibyte = w * 1024 + j * 4096;
            int lb = ibyte + lane * 16;
            int row = lb >> 6, colb = lb & 63;
            const char* src = (const char*)Bt + (size_t)(n0 + row) * 1024 + k0 * 2 + colb;
            gload_lds16(src, (char*)Bs + ibyte);
        }
        __syncthreads();
        short8 af[4], bf[4];
#pragma unroll
        for (int mi = 0; mi < 4; mi++) {
            int r = wm * 64 + mi * 16 + (lane & 15);
            int off = ((lane >> 4) * 16) ^ ((r & 3) << 4);
            af[mi] = *(const short8*)((const char*)As + r * 64 + off);
        }
#pragma unroll
        for (int ni = 0; ni < 4; ni++) {
            int n = wn * 64 + ni * 16 + (lane & 15);
            int off = ((lane >> 4) * 16) ^ ((n & 3) << 4);
            bf[ni] = *(const short8*)((const char*)Bs + n * 64 + off);
        }
#pragma unroll
        for (int mi = 0; mi < 4; mi++)
#pragma unroll
            for (int ni = 0; ni < 4; ni++)
                acc[mi][ni] = __builtin_amdgcn_mfma_f32_16x16x32_bf16(af[mi], bf[ni], acc[mi][ni], 0, 0, 0);
    }
#pragma unroll
    for (int mi = 0; mi < 4; mi++) {
        int row = wm * 64 + mi * 16 + ((lane >> 4) << 2);
#pragma unroll
        for (int ni = 0; ni < 4; ni++) {
            int col = n0 + wn * 64 + ni * 16 + (lane & 15);
            float bv = bias ? bias[col] : 0.0f;
#pragma unroll
            for (int q = 0; q < 4; q++)
                C[(m0 + row + q) * 512 + col] = acc[mi][ni][q] + bv;
        }
    }
}

// ---------------------------------------------------------------------------
// hgen: h[mL][k] = gelu(he[tIdx(mG)][k] + hd[bu(mG)][k]) -> bf16, pre-swizzled
// layout: byte = mL*1024 + (k>>6)*128 + ((j*16) ^ ((mL&7)<<4)), j = (k>>3)&7
// ---------------------------------------------------------------------------
__global__ __launch_bounds__(256) void hgen(const float* __restrict__ he,
                                            const float* __restrict__ hd,
                                            unsigned short* __restrict__ hP,
                                            int mBase) {
    int t = threadIdx.x;
    int mL = blockIdx.x * 4 + (t >> 6);
    int mG = mBase + mL;
    int c  = t & 63;                     // which 8-k chunk
    int tI = mG / 96;
    int u  = mG - tI * 96;
    int b  = tI >> 8;
    const float* e = he + (size_t)tI * 512 + c * 8;
    const float* d = hd + (size_t)(b * 96 + u) * 512 + c * 8;
    f32x4 e0 = *(const f32x4*)e,       d0 = *(const f32x4*)d;
    f32x4 e1 = *(const f32x4*)(e + 4), d1 = *(const f32x4*)(d + 4);
    uint4 pk;
    pk.x = (unsigned)f2bf(gelu_t(e0.x + d0.x)) | ((unsigned)f2bf(gelu_t(e0.y + d0.y)) << 16);
    pk.y = (unsigned)f2bf(gelu_t(e0.z + d0.z)) | ((unsigned)f2bf(gelu_t(e0.w + d0.w)) << 16);
    pk.z = (unsigned)f2bf(gelu_t(e1.x + d1.x)) | ((unsigned)f2bf(gelu_t(e1.y + d1.y)) << 16);
    pk.w = (unsigned)f2bf(gelu_t(e1.z + d1.z)) | ((unsigned)f2bf(gelu_t(e1.w + d1.w)) << 16);
    int slice = c >> 3, j = c & 7;
    *(uint4*)((char*)hP + (size_t)mL * 1024 + slice * 128 + ((j * 16) ^ ((mL & 7) << 4))) = pk;
}

// ---------------------------------------------------------------------------
// joint_gemm: out[m][v] = h[m] @ W2, BM=256 BN=256 BK=64, 512 thr (8 waves
// 2m x 4n, 128x64/wave).  Double-buffered global_load_lds, counted vmcnt(8),
// raw s_barrier + explicit waitcnt (never vmcnt(0) in steady state).
// LDS: (A 32KB + B 32KB) x 2 = 128KB.
// ---------------------------------------------------------------------------
__global__ __launch_bounds__(512, 2) void joint_gemm(const unsigned short* __restrict__ hP,
                                                     const unsigned short* __restrict__ W2t,
                                                     float* __restrict__ out) {
    __shared__ alignas(16) unsigned short As[2][256 * 64];
    __shared__ alignas(16) unsigned short Bs[2][256 * 64];
    int t = threadIdx.x;
    int lane = t & 63, w = t >> 6;
    int wm = w >> 2, wn = w & 3;           // 2m x 4n
    size_t m0 = (size_t)blockIdx.x * 256;
    int n0 = blockIdx.y * 256;

    // staging: pass p stages rows [p*64, p*64+64); wave w covers rows w*8+(lane>>3)
    const char* aSrc = (const char*)hP  + (m0 + (size_t)(w * 8) + (lane >> 3)) * 1024 + (lane & 7) * 16;
    const char* bSrc = (const char*)W2t + ((size_t)n0 + w * 8 + (lane >> 3)) * 1024 + (lane & 7) * 16;

    auto STAGE = [&](int buf, int kt2) {
        char* aDst = (char*)As[buf] + w * 1024;
        char* bDst = (char*)Bs[buf] + w * 1024;
        const char* as = aSrc + kt2 * 128;
        const char* bs = bSrc + kt2 * 128;
#pragma unroll
        for (int p = 0; p < 4; ++p) {
            gload_lds16(as + p * 65536, aDst + p * 8192);
            gload_lds16(bs + p * 65536, bDst + p * 8192);
        }
    };

    int l15 = lane & 15, lg = lane >> 4;
    int rxor = (l15 & 7) << 4;             // (row&7)<<4 == (l15&7)<<4 for both A rows and B cols
    int aC0 = (lg * 16) ^ rxor;            // kk=0 frag col byte
    int aC1 = (64 + lg * 16) ^ rxor;       // kk=1
    int aRow = wm * 16384 + l15 * 128;     // + mi*2048
    int bRow = wn * 8192  + l15 * 128;     // + ni*2048

    f32x4 acc[8][4] = {};

    // prologue: stage tiles 0 and 1
    STAGE(0, 0);
    STAGE(1, 1);
    asm volatile("s_waitcnt vmcnt(8)" ::: "memory");
    __builtin_amdgcn_sched_barrier(0);
    __builtin_amdgcn_s_barrier();
    __builtin_amdgcn_sched_barrier(0);

#pragma unroll
    for (int kt = 0; kt < 8; ++kt) {
        const char* Ab = (const char*)As[kt & 1];
        const char* Bb = (const char*)Bs[kt & 1];
        short8 a0[8], b0[4], a1[8], b1[4];
#pragma unroll
        for (int mi = 0; mi < 8; ++mi) a0[mi] = *(const short8*)(Ab + aRow + mi * 2048 + aC0);
#pragma unroll
        for (int ni = 0; ni < 4; ++ni) b0[ni] = *(const short8*)(Bb + bRow + ni * 2048 + aC0);
#pragma unroll
        for (int mi = 0; mi < 8; ++mi)
#pragma unroll
            for (int ni = 0; ni < 4; ++ni)
                acc[mi][ni] = __builtin_amdgcn_mfma_f32_16x16x32_bf16(a0[mi], b0[ni], acc[mi][ni], 0, 0, 0);
#pragma unroll
        for (int mi = 0; mi < 8; ++mi) a1[mi] = *(const short8*)(Ab + aRow + mi * 2048 + aC1);
#pragma unroll
        for (int ni = 0; ni < 4; ++ni) b1[ni] = *(const short8*)(Bb + bRow + ni * 2048 + aC1);
        // all reads of buf[cur] done -> safe for everyone to overwrite after barrier
        asm volatile("s_waitcnt lgkmcnt(0)" ::: "memory");
        __builtin_amdgcn_sched_barrier(0);
        __builtin_amdgcn_s_barrier();
        __builtin_amdgcn_sched_barrier(0);
        if (kt < 6) STAGE(kt & 1, kt + 2);
        __builtin_amdgcn_s_setprio(1);
#pragma unroll
        for (int mi = 0; mi < 8; ++mi)
#pragma unroll
            for (int ni = 0; ni < 4; ++ni)
                acc[mi][ni] = __builtin_amdgcn_mfma_f32_16x16x32_bf16(a1[mi], b1[ni], acc[mi][ni], 0, 0, 0);
        __builtin_amdgcn_s_setprio(0);
        // tile kt+1 must be landed before next iter reads it; keep newest 8 in flight
        if (kt < 6)       asm volatile("s_waitcnt vmcnt(8)" ::: "memory");
        else if (kt == 6) asm volatile("s_waitcnt vmcnt(0)" ::: "memory");
        if (kt < 7) {
            __builtin_amdgcn_sched_barrier(0);
            __builtin_amdgcn_s_barrier();
            __builtin_amdgcn_sched_barrier(0);
        }
    }

    // epilogue: C/D layout col=lane&15, row=(lane>>4)*4+q; nontemporal (write-once)
#pragma unroll
    for (int mi = 0; mi < 8; ++mi) {
        size_t row = m0 + wm * 128 + mi * 16 + (lg << 2);
#pragma unroll
        for (int ni = 0; ni < 4; ++ni) {
            int col = n0 + wn * 64 + ni * 16 + l15;
            float* o = out + row * 1024 + col;
            __builtin_nontemporal_store(acc[mi][ni][0], o);
            __builtin_nontemporal_store(acc[mi][ni][1], o + 1024);
            __builtin_nontemporal_store(acc[mi][ni][2], o + 2048);
            __builtin_nontemporal_store(acc[mi][ni][3], o + 3072);
        }
    }
}

// ---------------------------------------------------------------------------
// Fallback fused kernel (verified R1, 270us) — used only if ws is too small
// to materialize h in chunks of >= 12288 rows.
// ---------------------------------------------------------------------------
__global__ __launch_bounds__(512, 2) void joint_big(const float* __restrict__ he,
                                                    const float* __restrict__ hd,
                                                    const unsigned short* __restrict__ W2t,
                                                    float* __restrict__ out) {
    __shared__ alignas(16) unsigned short As[128 * 32];
    __shared__ alignas(16) unsigned short Bs[512 * 32];
    int t = threadIdx.x;
    int mt = blockIdx.x;
    int n0 = blockIdx.y * 512;
    size_t m0 = (size_t)mt * 128;
    int lane = t & 63, w = t >> 6;
    int wm = w >> 2, wn = w & 3;

    int rA = t >> 2, cg = t & 3;
    int mrow = (int)m0 + rA;
    int tIdx = mrow / 96;
    int u    = mrow - tIdx * 96;
    int b    = tIdx >> 8;
    const float* heRow = he + (size_t)tIdx * 512 + cg * 8;
    const float* hdRow = hd + (size_t)(b * 96 + u) * 512 + cg * 8;
    int aoff = rA * 64 + ((cg * 16) ^ ((rA & 3) << 4));

    f32x4 acc[4][8] = {};

    for (int kt = 0; kt < 16; ++kt) {
        int k0 = kt * 32;
        f32x4 e0 = *(const f32x4*)(heRow + k0);
        f32x4 d0 = *(const f32x4*)(hdRow + k0);
        f32x4 e1 = *(const f32x4*)(heRow + k0 + 4);
        f32x4 d1 = *(const f32x4*)(hdRow + k0 + 4);
        float h0 = gelu_t(e0.x + d0.x), h1 = gelu_t(e0.y + d0.y);
        float h2 = gelu_t(e0.z + d0.z), h3 = gelu_t(e0.w + d0.w);
        float h4 = gelu_t(e1.x + d1.x), h5 = gelu_t(e1.y + d1.y);
        float h6 = gelu_t(e1.z + d1.z), h7 = gelu_t(e1.w + d1.w);
        uint4 pk;
        pk.x = (unsigned)f2bf(h0) | ((unsigned)f2bf(h1) << 16);
        pk.y = (unsigned)f2bf(h2) | ((unsigned)f2bf(h3) << 16);
        pk.z = (unsigned)f2bf(h4) | ((unsigned)f2bf(h5) << 16);
        pk.w = (unsigned)f2bf(h6) | ((unsigned)f2bf(h7) << 16);
        __syncthreads();
        *(uint4*)((char*)As + aoff) = pk;
#pragma unroll
        for (int j = 0; j < 4; j++) {
            int ibyte = w * 4096 + j * 1024;
            int lb = ibyte + lane * 16;
            int row = lb >> 6, colb = lb & 63;
            const char* src = (const char*)W2t + (size_t)(n0 + row) * 1024 + k0 * 2 + colb;
            gload_lds16(src, (char*)Bs + ibyte);
        }
        __syncthreads();
        short8 af[4], bfr[8];
#pragma unroll
        for (int mi = 0; mi < 4; mi++) {
            int r = wm * 64 + mi * 16 + (lane & 15);
            int off = ((lane >> 4) * 16) ^ ((r & 3) << 4);
            af[mi] = *(const short8*)((const char*)As + r * 64 + off);
        }
#pragma unroll
        for (int ni = 0; ni < 8; ni++) {
            int n = wn * 128 + ni * 16 + (lane & 15);
            int off = ((lane >> 4) * 16) ^ ((n & 3) << 4);
            bfr[ni] = *(const short8*)((const char*)Bs + n * 64 + off);
        }
#pragma unroll
        for (int mi = 0; mi < 4; mi++)
#pragma unroll
            for (int ni = 0; ni < 8; ni++)
                acc[mi][ni] = __builtin_amdgcn_mfma_f32_16x16x32_bf16(af[mi], bfr[ni], acc[mi][ni], 0, 0, 0);
    }
#pragma unroll
    for (int mi = 0; mi < 4; mi++) {
        int row = wm * 64 + mi * 16 + ((lane >> 4) << 2);
        size_t mg = m0 + row;
#pragma unroll
        for (int ni = 0; ni < 8; ni++) {
            int col = n0 + wn * 128 + ni * 16 + (lane & 15);
            float* o = out + mg * 1024 + col;
            o[0]    = acc[mi][ni][0];
            o[1024] = acc[mi][ni][1];
            o[2048] = acc[mi][ni][2];
            o[3072] = acc[mi][ni][3];
        }
    }
}

extern "C" void kernel_launch(void* const* d_in, const int* in_sizes, int n_in,
                              void* d_out, int out_size, void* d_ws, size_t ws_size,
                              hipStream_t stream) {
    const float* enc = (const float*)d_in[0];   // (4,256,512)
    const float* dec = (const float*)d_in[1];   // (4,96,512)
    const float* W1  = (const float*)d_in[2];   // (1024,512)
    const float* b1  = (const float*)d_in[3];   // (512,)
    const float* W2  = (const float*)d_in[4];   // (512,1024)
    float* out = (float*)d_out;                 // (4,256,96,1024) f32

    char* ws = (char*)d_ws;
    float* he = (float*)(ws);                               // 1024x512 f32 (bias folded)
    float* hd = (float*)(ws + 2097152);                     //  384x512 f32
    unsigned short* Wet = (unsigned short*)(ws + 2883584);  // 512x512 bf16 swz (old layout)
    unsigned short* Wdt = (unsigned short*)(ws + 3407872);  // 512x512 bf16 swz (old layout)
    unsigned short* W2t = (unsigned short*)(ws + 3932160);  // 1024x512 bf16 swz (layout per path)
    unsigned short* hP  = (unsigned short*)(ws + 4980736);  // chunkRows x 512 bf16 swz

    transpose_swz<<<dim3(8, 8), 256, 0, stream>>>(W1,             Wet, 512, 512);
    transpose_swz<<<dim3(8, 8), 256, 0, stream>>>(W1 + 512 * 512, Wdt, 512, 512);

    gemm_small<<<dim3(8, 4), 256, 0, stream>>>(enc, Wet, b1,      he);   // he + b1
    gemm_small<<<dim3(3, 4), 256, 0, stream>>>(dec, Wdt, nullptr, hd);   // hd

    size_t avail = ws_size > 4980736 ? ws_size - 4980736 : 0;
    int nch = 0;
    for (int d : {1, 2, 3, 4, 6, 8})
        if ((size_t)(98304 / d) * 1024 <= avail) { nch = d; break; }

    if (nch) {
        transpose_swz64<<<dim3(8, 16), 256, 0, stream>>>(W2, W2t, 512, 1024);
        int rows = 98304 / nch;
        for (int c = 0; c < nch; ++c) {
            int mBase = c * rows;
            hgen<<<rows / 4, 256, 0, stream>>>(he, hd, hP, mBase);
            joint_gemm<<<dim3(rows / 256, 4), 512, 0, stream>>>(hP, W2t, out + (size_t)mBase * 1024);
        }
    } else {
        transpose_swz<<<dim3(8, 16), 256, 0, stream>>>(W2, W2t, 512, 1024);
        joint_big<<<dim3(768, 2), 512, 0, stream>>>(he, hd, W2t, out);
    }
}

// Round 3
// 244.230 us; speedup vs baseline: 1.2719x; 1.1113x over previous
//
#include <hip/hip_runtime.h>
#include <hip/hip_bf16.h>

typedef __attribute__((ext_vector_type(8))) short short8;   // 8 bf16 = 4 VGPR (MFMA A/B frag)
typedef __attribute__((ext_vector_type(4))) float f32x4;    // MFMA C/D frag

__device__ __forceinline__ unsigned short f2bf(float f) {
    union { __hip_bfloat16 h; unsigned short u; } cv;
    cv.h = __float2bfloat16(f);   // RNE
    return cv.u;
}

// jax.nn.gelu(approximate=True): 0.5x(1+tanh(sqrt(2/pi)(x+0.044715x^3))) == x*e/(e+1), e=exp(2*inner)
__device__ __forceinline__ float gelu_t(float x) {
    float e = __expf(1.5957691216057308f * x * __builtin_fmaf(0.044715f, x * x, 1.0f));
    return x * (e / (e + 1.0f));
}

__device__ __forceinline__ void gload_lds16(const void* g, void* l) {
    __builtin_amdgcn_global_load_lds((const __attribute__((address_space(1))) unsigned int*)g,
                                     (__attribute__((address_space(3))) unsigned int*)l, 16, 0, 0);
}

// XOR swizzle key for 64B LDS rows: row r -> ((r>>1)&3)<<4.
// Quarter-wave frag reads hit all 8 bank-quads (2-way = free), unlike (r&3) (4-way).
__device__ __forceinline__ int swzkey(int r) { return ((r >> 1) & 3) << 4; }

// ---------------------------------------------------------------------------
// Fused transpose + f32->bf16 + pre-swizzle for We, Wd, W2 (one launch).
// out[n][k], 64B k-slices, inner byte ^= swzkey(n).
// z=0: We (W1 rows 0-511), z=1: Wd (W1 rows 512-1023), z=2: W2. K=512 all.
// ---------------------------------------------------------------------------
__global__ __launch_bounds__(256) void transpose_all(const float* __restrict__ W1,
                                                     const float* __restrict__ W2,
                                                     unsigned short* __restrict__ Wet,
                                                     unsigned short* __restrict__ Wdt,
                                                     unsigned short* __restrict__ W2t) {
    int z = blockIdx.z;
    if (z < 2 && blockIdx.y >= 8) return;      // We/Wd have N=512
    const float* in = (z == 0) ? W1 : (z == 1) ? (W1 + 512 * 512) : W2;
    unsigned short* out = (z == 0) ? Wet : (z == 1) ? Wdt : W2t;
    int N = (z == 2) ? 1024 : 512;

    __shared__ float tile[64][65];
    int k0 = blockIdx.x * 64, n0 = blockIdx.y * 64;
    int t = threadIdx.x;
    int c = t & 63, r0 = t >> 6;
#pragma unroll
    for (int i = 0; i < 16; i++) {
        int r = r0 + i * 4;
        tile[r][c] = in[(size_t)(k0 + r) * N + n0 + c];
    }
    __syncthreads();
    int kk = t & 15;       // 4 k's = 8 bytes per thread
    int nl0 = t >> 4;
#pragma unroll
    for (int i = 0; i < 4; i++) {
        int nl = nl0 + i * 16;
        int n  = n0 + nl;
        unsigned short b0 = f2bf(tile[kk * 4 + 0][nl]);
        unsigned short b1 = f2bf(tile[kk * 4 + 1][nl]);
        unsigned short b2 = f2bf(tile[kk * 4 + 2][nl]);
        unsigned short b3 = f2bf(tile[kk * 4 + 3][nl]);
        uint2 v;
        v.x = (unsigned)b0 | ((unsigned)b1 << 16);
        v.y = (unsigned)b2 | ((unsigned)b3 << 16);
        int byte_in_chunk = kk * 8;                     // 0..127 (two 64B slices)
        int slice = byte_in_chunk & ~63;
        int off   = (byte_in_chunk & 63) ^ swzkey(n);
        size_t obyte = (size_t)n * 1024 + (size_t)k0 * 2 + slice + off;
        *(uint2*)((char*)out + obyte) = v;
    }
}

// ---------------------------------------------------------------------------
// he/hd GEMM (one launch): C[M][512] = A[M][512] @ Bt^T (+bias).
// bx<8: enc->he (+b1), bx>=8: dec->hd. BM=128 BN=128 BK=32, 256 thr.
// ---------------------------------------------------------------------------
__global__ __launch_bounds__(256, 2) void gemm_small(const float* __restrict__ enc,
                                                     const float* __restrict__ dec,
                                                     const unsigned short* __restrict__ Wet,
                                                     const unsigned short* __restrict__ Wdt,
                                                     const float* __restrict__ b1,
                                                     float* __restrict__ he,
                                                     float* __restrict__ hd) {
    bool isEnc = blockIdx.x < 8;
    const float* A = isEnc ? enc : dec;
    const unsigned short* Bt = isEnc ? Wet : Wdt;
    const float* bias = isEnc ? b1 : nullptr;
    float* C = isEnc ? he : hd;
    size_t m0 = (size_t)(isEnc ? blockIdx.x : blockIdx.x - 8) * 128;

    __shared__ alignas(16) unsigned short As[128 * 32];
    __shared__ alignas(16) unsigned short Bs[128 * 32];
    int t = threadIdx.x;
    int n0 = blockIdx.y * 128;
    int lane = t & 63, w = t >> 6;
    int wm = w >> 1, wn = w & 1;
    int rA = t >> 3, cg = t & 7;
    f32x4 acc[4][4] = {};

    for (int kt = 0; kt < 16; ++kt) {
        int k0 = kt * 32;
        __syncthreads();
#pragma unroll
        for (int p = 0; p < 4; p++) {
            int r = rA + p * 32;
            f32x4 v = *(const f32x4*)&A[(m0 + r) * 512 + k0 + cg * 4];
            uint2 pk;
            pk.x = (unsigned)f2bf(v.x) | ((unsigned)f2bf(v.y) << 16);
            pk.y = (unsigned)f2bf(v.z) | ((unsigned)f2bf(v.w) << 16);
            int off = (cg * 8) ^ swzkey(r);
            *(uint2*)((char*)As + r * 64 + off) = pk;
        }
#pragma unroll
        for (int j = 0; j < 2; j++) {
            int ibyte = w * 1024 + j * 4096;
            int lb = ibyte + lane * 16;
            int row = lb >> 6, colb = lb & 63;
            const char* src = (const char*)Bt + (size_t)(n0 + row) * 1024 + k0 * 2 + colb;
            gload_lds16(src, (char*)Bs + ibyte);
        }
        __syncthreads();
        short8 af[4], bf[4];
#pragma unroll
        for (int mi = 0; mi < 4; mi++) {
            int r = wm * 64 + mi * 16 + (lane & 15);
            int off = ((lane >> 4) * 16) ^ swzkey(r);
            af[mi] = *(const short8*)((const char*)As + r * 64 + off);
        }
#pragma unroll
        for (int ni = 0; ni < 4; ni++) {
            int n = wn * 64 + ni * 16 + (lane & 15);
            int off = ((lane >> 4) * 16) ^ swzkey(n);
            bf[ni] = *(const short8*)((const char*)Bs + n * 64 + off);
        }
#pragma unroll
        for (int mi = 0; mi < 4; mi++)
#pragma unroll
            for (int ni = 0; ni < 4; ni++)
                acc[mi][ni] = __builtin_amdgcn_mfma_f32_16x16x32_bf16(af[mi], bf[ni], acc[mi][ni], 0, 0, 0);
    }
#pragma unroll
    for (int mi = 0; mi < 4; mi++) {
        int row = wm * 64 + mi * 16 + ((lane >> 4) << 2);
#pragma unroll
        for (int ni = 0; ni < 4; ni++) {
            int col = n0 + wn * 64 + ni * 16 + (lane & 15);
            float bv = bias ? bias[col] : 0.0f;
#pragma unroll
            for (int q = 0; q < 4; q++)
                C[(m0 + row + q) * 512 + col] = acc[mi][ni][q] + bv;
        }
    }
}

// ---------------------------------------------------------------------------
// Fused joint: out[m][v] = gelu(he[t(m)]+hd[b,u(m)]) @ W2.
// BM=128 BN=512 BK=32, 512 thr (8 waves 2m x 4n, 64x128/wave), 16 K-steps.
// Double-buffered A (gelu->ds_write) and B (global_load_lds), ONE barrier/step,
// all memory issued at step top (B(t+1), he/hd(t+2)) so the barrier drain is
// ~free. LDS 80KB.
// ---------------------------------------------------------------------------
__global__ __launch_bounds__(512, 2) void joint_fused(const float* __restrict__ he,
                                                      const float* __restrict__ hd,
                                                      const unsigned short* __restrict__ W2t,
                                                      float* __restrict__ out) {
    __shared__ alignas(16) unsigned short As[2][128 * 32];   //  8 KB x2
    __shared__ alignas(16) unsigned short Bs[2][512 * 32];   // 32 KB x2
    int t = threadIdx.x;
    int lane = t & 63, w = t >> 6;
    int wm = w >> 2, wn = w & 3;           // 2m x 4n
    size_t m0 = (size_t)blockIdx.x * 128;
    int n0 = blockIdx.y * 512;

    // ---- A-gen mapping (fixed per thread): row rA = t>>2, 8 k's at cg*8
    int rA = t >> 2, cg = t & 3;
    int mrow = (int)m0 + rA;
    int tI = mrow / 96;                    // b*256+t index into he (0..1023)
    int u  = mrow - tI * 96;
    const float* eP = he + (size_t)tI * 512 + cg * 8;
    const float* dP = hd + (size_t)((tI >> 8) * 96 + u) * 512 + cg * 8;
    int aoff = rA * 64 + ((cg * 16) ^ swzkey(rA));

    // ---- B staging: wave w covers Bs rows [w*64, w*64+64), 4 x 1KB insts
    const char* bSrc[4];
#pragma unroll
    for (int i = 0; i < 4; i++) {
        int row = w * 64 + i * 16 + (lane >> 2);
        bSrc[i] = (const char*)W2t + (size_t)(n0 + row) * 1024 + (lane & 3) * 16;
    }

    // ---- fragment byte offsets
    int l15 = lane & 15, lg = lane >> 4;
    int aOff[4], bOff[8];
#pragma unroll
    for (int mi = 0; mi < 4; mi++) {
        int r = wm * 64 + mi * 16 + l15;
        aOff[mi] = r * 64 + ((lg * 16) ^ swzkey(r));
    }
#pragma unroll
    for (int ni = 0; ni < 8; ni++) {
        int n = wn * 128 + ni * 16 + l15;
        bOff[ni] = n * 64 + ((lg * 16) ^ swzkey(n));
    }

    f32x4 acc[4][8] = {};
    f32x4 er[2][2], dr[2][2];              // 2-slot rotation, static idx (unrolled)

#define LOADED(slot, kt)  do { \
        er[slot][0] = *(const f32x4*)(eP + (kt) * 32); \
        er[slot][1] = *(const f32x4*)(eP + (kt) * 32 + 4); \
        dr[slot][0] = *(const f32x4*)(dP + (kt) * 32); \
        dr[slot][1] = *(const f32x4*)(dP + (kt) * 32 + 4); } while (0)

#define STAGE_B(buf, kt)  do { \
        _Pragma("unroll") \
        for (int i = 0; i < 4; i++) \
            gload_lds16(bSrc[i] + (kt) * 64, (char*)Bs[buf] + w * 4096 + i * 1024); } while (0)

#define GELU_A(buf, slot) do { \
        uint4 pk; \
        pk.x = (unsigned)f2bf(gelu_t(er[slot][0].x + dr[slot][0].x)) | \
               ((unsigned)f2bf(gelu_t(er[slot][0].y + dr[slot][0].y)) << 16); \
        pk.y = (unsigned)f2bf(gelu_t(er[slot][0].z + dr[slot][0].z)) | \
               ((unsigned)f2bf(gelu_t(er[slot][0].w + dr[slot][0].w)) << 16); \
        pk.z = (unsigned)f2bf(gelu_t(er[slot][1].x + dr[slot][1].x)) | \
               ((unsigned)f2bf(gelu_t(er[slot][1].y + dr[slot][1].y)) << 16); \
        pk.w = (unsigned)f2bf(gelu_t(er[slot][1].z + dr[slot][1].z)) | \
               ((unsigned)f2bf(gelu_t(er[slot][1].w + dr[slot][1].w)) << 16); \
        *(uint4*)((char*)As[buf] + aoff) = pk; } while (0)

    // ---- prologue: tile 0 fully staged, tile-1 regs in flight
    STAGE_B(0, 0);
    LOADED(0, 0);
    LOADED(1, 1);
    GELU_A(0, 0);
    __syncthreads();

#pragma unroll
    for (int kt = 0; kt < 16; ++kt) {
        const int cur = kt & 1, nxt = cur ^ 1;
        // issue next-tile staging and next-next reg loads first (fly under compute)
        if (kt < 15) STAGE_B(nxt, kt + 1);
        if (kt < 14) LOADED(cur, kt + 2);                 // slot kt&1 free: consumed last step
        if (kt < 15) GELU_A(nxt, nxt);                    // A(kt+1) from regs slot (kt+1)&1
        // fragments + MFMA from cur
        short8 a[4];
#pragma unroll
        for (int mi = 0; mi < 4; mi++) a[mi] = *(const short8*)((const char*)As[cur] + aOff[mi]);
        __builtin_amdgcn_s_setprio(1);
#pragma unroll
        for (int ni = 0; ni < 8; ni++) {
            short8 b = *(const short8*)((const char*)Bs[cur] + bOff[ni]);
#pragma unroll
            for (int mi = 0; mi < 4; mi++)
                acc[mi][ni] = __builtin_amdgcn_mfma_f32_16x16x32_bf16(a[mi], b, acc[mi][ni], 0, 0, 0);
        }
        __builtin_amdgcn_s_setprio(0);
        if (kt < 15) __syncthreads();
    }
#undef LOADED
#undef STAGE_B
#undef GELU_A

    // ---- epilogue: C/D layout col=lane&15, row=(lane>>4)*4+q; nontemporal f32
#pragma unroll
    for (int mi = 0; mi < 4; mi++) {
        size_t row = m0 + wm * 64 + mi * 16 + (lg << 2);
#pragma unroll
        for (int ni = 0; ni < 8; ni++) {
            int col = n0 + wn * 128 + ni * 16 + l15;
            float* o = out + row * 1024 + col;
            __builtin_nontemporal_store(acc[mi][ni][0], o);
            __builtin_nontemporal_store(acc[mi][ni][1], o + 1024);
            __builtin_nontemporal_store(acc[mi][ni][2], o + 2048);
            __builtin_nontemporal_store(acc[mi][ni][3], o + 3072);
        }
    }
}

extern "C" void kernel_launch(void* const* d_in, const int* in_sizes, int n_in,
                              void* d_out, int out_size, void* d_ws, size_t ws_size,
                              hipStream_t stream) {
    const float* enc = (const float*)d_in[0];   // (4,256,512)
    const float* dec = (const float*)d_in[1];   // (4,96,512)
    const float* W1  = (const float*)d_in[2];   // (1024,512)
    const float* b1  = (const float*)d_in[3];   // (512,)
    const float* W2  = (const float*)d_in[4];   // (512,1024)
    float* out = (float*)d_out;                 // (4,256,96,1024) f32

    char* ws = (char*)d_ws;
    float* he = (float*)(ws);                               // 1024x512 f32 (b1 folded)
    float* hd = (float*)(ws + 2097152);                     //  384x512 f32
    unsigned short* Wet = (unsigned short*)(ws + 2883584);  // 512x512 bf16 swz
    unsigned short* Wdt = (unsigned short*)(ws + 3407872);  // 512x512 bf16 swz
    unsigned short* W2t = (unsigned short*)(ws + 3932160);  // 1024x512 bf16 swz

    transpose_all<<<dim3(8, 16, 3), 256, 0, stream>>>(W1, W2, Wet, Wdt, W2t);
    gemm_small<<<dim3(11, 4), 256, 0, stream>>>(enc, dec, Wet, Wdt, b1, he, hd);
    joint_fused<<<dim3(768, 2), 512, 0, stream>>>(he, hd, W2t, out);
}

// Round 4
// 207.164 us; speedup vs baseline: 1.4995x; 1.1789x over previous
//
#include <hip/hip_runtime.h>
#include <hip/hip_bf16.h>

typedef __attribute__((ext_vector_type(8))) short short8;   // 8 bf16 = 4 VGPR (MFMA A/B frag)
typedef __attribute__((ext_vector_type(4))) float f32x4;    // MFMA C/D frag

__device__ __forceinline__ unsigned short f2bf(float f) {
    union { __hip_bfloat16 h; unsigned short u; } cv;
    cv.h = __float2bfloat16(f);   // RNE
    return cv.u;
}

// jax.nn.gelu(approximate=True): 0.5x(1+tanh(sqrt(2/pi)(x+0.044715x^3))) == x*e/(e+1), e=exp(2*inner)
__device__ __forceinline__ float gelu_t(float x) {
    float e = __expf(1.5957691216057308f * x * __builtin_fmaf(0.044715f, x * x, 1.0f));
    return x * (e / (e + 1.0f));
}

__device__ __forceinline__ void gload_lds16(const void* g, void* l) {
    __builtin_amdgcn_global_load_lds((const __attribute__((address_space(1))) unsigned int*)g,
                                     (__attribute__((address_space(3))) unsigned int*)l, 16, 0, 0);
}

// XOR swizzle key for 64B LDS rows: row r -> ((r>>1)&3)<<4 (2-way = free, verified R3: conflicts==0)
__device__ __forceinline__ int swzkey(int r) { return ((r >> 1) & 3) << 4; }

// ---------------------------------------------------------------------------
// Fused transpose + f32->bf16 + pre-swizzle for We, Wd, W2 (one launch). (verified R3)
// ---------------------------------------------------------------------------
__global__ __launch_bounds__(256) void transpose_all(const float* __restrict__ W1,
                                                     const float* __restrict__ W2,
                                                     unsigned short* __restrict__ Wet,
                                                     unsigned short* __restrict__ Wdt,
                                                     unsigned short* __restrict__ W2t) {
    int z = blockIdx.z;
    if (z < 2 && blockIdx.y >= 8) return;      // We/Wd have N=512
    const float* in = (z == 0) ? W1 : (z == 1) ? (W1 + 512 * 512) : W2;
    unsigned short* out = (z == 0) ? Wet : (z == 1) ? Wdt : W2t;
    int N = (z == 2) ? 1024 : 512;

    __shared__ float tile[64][65];
    int k0 = blockIdx.x * 64, n0 = blockIdx.y * 64;
    int t = threadIdx.x;
    int c = t & 63, r0 = t >> 6;
#pragma unroll
    for (int i = 0; i < 16; i++) {
        int r = r0 + i * 4;
        tile[r][c] = in[(size_t)(k0 + r) * N + n0 + c];
    }
    __syncthreads();
    int kk = t & 15;
    int nl0 = t >> 4;
#pragma unroll
    for (int i = 0; i < 4; i++) {
        int nl = nl0 + i * 16;
        int n  = n0 + nl;
        unsigned short b0 = f2bf(tile[kk * 4 + 0][nl]);
        unsigned short b1 = f2bf(tile[kk * 4 + 1][nl]);
        unsigned short b2 = f2bf(tile[kk * 4 + 2][nl]);
        unsigned short b3 = f2bf(tile[kk * 4 + 3][nl]);
        uint2 v;
        v.x = (unsigned)b0 | ((unsigned)b1 << 16);
        v.y = (unsigned)b2 | ((unsigned)b3 << 16);
        int byte_in_chunk = kk * 8;
        int slice = byte_in_chunk & ~63;
        int off   = (byte_in_chunk & 63) ^ swzkey(n);
        size_t obyte = (size_t)n * 1024 + (size_t)k0 * 2 + slice + off;
        *(uint2*)((char*)out + obyte) = v;
    }
}

// ---------------------------------------------------------------------------
// he/hd GEMM (one launch): C[M][512] = A[M][512] @ Bt^T (+bias). (verified R3)
// ---------------------------------------------------------------------------
__global__ __launch_bounds__(256, 2) void gemm_small(const float* __restrict__ enc,
                                                     const float* __restrict__ dec,
                                                     const unsigned short* __restrict__ Wet,
                                                     const unsigned short* __restrict__ Wdt,
                                                     const float* __restrict__ b1,
                                                     float* __restrict__ he,
                                                     float* __restrict__ hd) {
    bool isEnc = blockIdx.x < 8;
    const float* A = isEnc ? enc : dec;
    const unsigned short* Bt = isEnc ? Wet : Wdt;
    const float* bias = isEnc ? b1 : nullptr;
    float* C = isEnc ? he : hd;
    size_t m0 = (size_t)(isEnc ? blockIdx.x : blockIdx.x - 8) * 128;

    __shared__ alignas(16) unsigned short As[128 * 32];
    __shared__ alignas(16) unsigned short Bs[128 * 32];
    int t = threadIdx.x;
    int n0 = blockIdx.y * 128;
    int lane = t & 63, w = t >> 6;
    int wm = w >> 1, wn = w & 1;
    int rA = t >> 3, cg = t & 7;
    f32x4 acc[4][4] = {};

    for (int kt = 0; kt < 16; ++kt) {
        int k0 = kt * 32;
        __syncthreads();
#pragma unroll
        for (int p = 0; p < 4; p++) {
            int r = rA + p * 32;
            f32x4 v = *(const f32x4*)&A[(m0 + r) * 512 + k0 + cg * 4];
            uint2 pk;
            pk.x = (unsigned)f2bf(v.x) | ((unsigned)f2bf(v.y) << 16);
            pk.y = (unsigned)f2bf(v.z) | ((unsigned)f2bf(v.w) << 16);
            int off = (cg * 8) ^ swzkey(r);
            *(uint2*)((char*)As + r * 64 + off) = pk;
        }
#pragma unroll
        for (int j = 0; j < 2; j++) {
            int ibyte = w * 1024 + j * 4096;
            int lb = ibyte + lane * 16;
            int row = lb >> 6, colb = lb & 63;
            const char* src = (const char*)Bt + (size_t)(n0 + row) * 1024 + k0 * 2 + colb;
            gload_lds16(src, (char*)Bs + ibyte);
        }
        __syncthreads();
        short8 af[4], bf[4];
#pragma unroll
        for (int mi = 0; mi < 4; mi++) {
            int r = wm * 64 + mi * 16 + (lane & 15);
            int off = ((lane >> 4) * 16) ^ swzkey(r);
            af[mi] = *(const short8*)((const char*)As + r * 64 + off);
        }
#pragma unroll
        for (int ni = 0; ni < 4; ni++) {
            int n = wn * 64 + ni * 16 + (lane & 15);
            int off = ((lane >> 4) * 16) ^ swzkey(n);
            bf[ni] = *(const short8*)((const char*)Bs + n * 64 + off);
        }
#pragma unroll
        for (int mi = 0; mi < 4; mi++)
#pragma unroll
            for (int ni = 0; ni < 4; ni++)
                acc[mi][ni] = __builtin_amdgcn_mfma_f32_16x16x32_bf16(af[mi], bf[ni], acc[mi][ni], 0, 0, 0);
    }
#pragma unroll
    for (int mi = 0; mi < 4; mi++) {
        int row = wm * 64 + mi * 16 + ((lane >> 4) << 2);
#pragma unroll
        for (int ni = 0; ni < 4; ni++) {
            int col = n0 + wn * 64 + ni * 16 + (lane & 15);
            float bv = bias ? bias[col] : 0.0f;
#pragma unroll
            for (int q = 0; q < 4; q++)
                C[(m0 + row + q) * 512 + col] = acc[mi][ni][q] + bv;
        }
    }
}

// ---------------------------------------------------------------------------
// Fused joint: out[m][v] = gelu(he[t(m)]+hd[b,u(m)]) @ W2.
// BM=128 BN=512 BK=32, 512 thr (8 waves 2m x 4n, 64x128/wave), 16 K-steps.
// Changes vs R3: raw s_barrier + counted vmcnt(4) (B-stage lands, he/hd reg
// loads stay in flight across barriers — no full drains); epilogue staged
// through per-wave LDS pad -> 16B/lane contiguous NT dwordx4 stores.
// ---------------------------------------------------------------------------
__global__ __launch_bounds__(512, 2) void joint_fused(const float* __restrict__ he,
                                                      const float* __restrict__ hd,
                                                      const unsigned short* __restrict__ W2t,
                                                      float* __restrict__ out) {
    __shared__ alignas(16) char lds[81920];
    // carve: As[0]=0, As[1]=8192, Bs[0]=16384, Bs[1]=49152  (A 8KB x2, B 32KB x2)
    int t = threadIdx.x;
    int lane = t & 63, w = t >> 6;
    int wm = w >> 2, wn = w & 3;           // 2m x 4n
    int bx = blockIdx.x;                   // 0..767, XCD-swizzle (768 % 8 == 0 -> bijective)
    int mt = (bx & 7) * 96 + (bx >> 3);
    size_t m0 = (size_t)mt * 128;
    int n0 = blockIdx.y * 512;

    // ---- A-gen mapping (fixed per thread): row rA = t>>2, 8 k's at cg*8
    int rA = t >> 2, cg = t & 3;
    int mrow = (int)m0 + rA;
    int tI = mrow / 96;                    // b*256+t index into he (0..1023)
    int u  = mrow - tI * 96;
    const float* eP = he + (size_t)tI * 512 + cg * 8;
    const float* dP = hd + (size_t)((tI >> 8) * 96 + u) * 512 + cg * 8;
    int aoff = rA * 64 + ((cg * 16) ^ swzkey(rA));

    // ---- B staging: wave w covers Bs rows [w*64, w*64+64), 4 x 1KB insts
    const char* bSrc[4];
#pragma unroll
    for (int i = 0; i < 4; i++) {
        int row = w * 64 + i * 16 + (lane >> 2);
        bSrc[i] = (const char*)W2t + (size_t)(n0 + row) * 1024 + (lane & 3) * 16;
    }

    // ---- fragment byte offsets
    int l15 = lane & 15, lg = lane >> 4;
    int aOff[4], bOff[8];
#pragma unroll
    for (int mi = 0; mi < 4; mi++) {
        int r = wm * 64 + mi * 16 + l15;
        aOff[mi] = r * 64 + ((lg * 16) ^ swzkey(r));
    }
#pragma unroll
    for (int ni = 0; ni < 8; ni++) {
        int n = wn * 128 + ni * 16 + l15;
        bOff[ni] = 16384 + n * 64 + ((lg * 16) ^ swzkey(n));   // +Bs base
    }

    f32x4 acc[4][8] = {};
    f32x4 er[2][2], dr[2][2];              // 2-slot rotation, static idx (unrolled)

#define LOADED(slot, kt)  do { \
        er[slot][0] = *(const f32x4*)(eP + (kt) * 32); \
        er[slot][1] = *(const f32x4*)(eP + (kt) * 32 + 4); \
        dr[slot][0] = *(const f32x4*)(dP + (kt) * 32); \
        dr[slot][1] = *(const f32x4*)(dP + (kt) * 32 + 4); } while (0)

#define STAGE_B(buf, kt)  do { \
        _Pragma("unroll") \
        for (int i = 0; i < 4; i++) \
            gload_lds16(bSrc[i] + (kt) * 64, lds + 16384 + (buf) * 32768 + w * 4096 + i * 1024); } while (0)

#define GELU_A(buf, slot) do { \
        uint4 pk; \
        pk.x = (unsigned)f2bf(gelu_t(er[slot][0].x + dr[slot][0].x)) | \
               ((unsigned)f2bf(gelu_t(er[slot][0].y + dr[slot][0].y)) << 16); \
        pk.y = (unsigned)f2bf(gelu_t(er[slot][0].z + dr[slot][0].z)) | \
               ((unsigned)f2bf(gelu_t(er[slot][0].w + dr[slot][0].w)) << 16); \
        pk.z = (unsigned)f2bf(gelu_t(er[slot][1].x + dr[slot][1].x)) | \
               ((unsigned)f2bf(gelu_t(er[slot][1].y + dr[slot][1].y)) << 16); \
        pk.w = (unsigned)f2bf(gelu_t(er[slot][1].z + dr[slot][1].z)) | \
               ((unsigned)f2bf(gelu_t(er[slot][1].w + dr[slot][1].w)) << 16); \
        *(uint4*)(lds + (buf) * 8192 + aoff) = pk; } while (0)

    // ---- prologue: B(0) staged, regs tile0+tile1 in flight, A(0) written
    STAGE_B(0, 0);
    LOADED(0, 0);
    LOADED(1, 1);
    GELU_A(0, 0);                          // compiler waits tile-0 reg loads
    asm volatile("s_waitcnt lgkmcnt(0)" ::: "memory");
    asm volatile("s_waitcnt vmcnt(4)" ::: "memory");   // B(0) landed; tile-1 regs in flight
    __builtin_amdgcn_sched_barrier(0);
    __builtin_amdgcn_s_barrier();
    __builtin_amdgcn_sched_barrier(0);

#pragma unroll
    for (int kt = 0; kt < 16; ++kt) {
        const int cur = kt & 1, nxt = cur ^ 1;
        // issue next-tile staging and next-next reg loads first (fly under compute)
        if (kt < 15) STAGE_B(nxt, kt + 1);
        if (kt < 14) LOADED(cur, kt + 2);                 // slot kt&1 free: consumed last step
        if (kt < 15) GELU_A(nxt, nxt);                    // A(kt+1) from regs slot (kt+1)&1
        // fragments + MFMA from cur
        short8 a[4];
#pragma unroll
        for (int mi = 0; mi < 4; mi++) a[mi] = *(const short8*)(lds + cur * 8192 + aOff[mi]);
        __builtin_amdgcn_s_setprio(1);
#pragma unroll
        for (int ni = 0; ni < 8; ni++) {
            short8 b = *(const short8*)(lds + cur * 32768 + bOff[ni]);
#pragma unroll
            for (int mi = 0; mi < 4; mi++)
                acc[mi][ni] = __builtin_amdgcn_mfma_f32_16x16x32_bf16(a[mi], b, acc[mi][ni], 0, 0, 0);
        }
        __builtin_amdgcn_s_setprio(0);
        if (kt < 15) {
            // own frag reads + A(nxt) ds_write complete; B(nxt) landed; he/hd regs stay in flight
            asm volatile("s_waitcnt lgkmcnt(0)" ::: "memory");
            __builtin_amdgcn_sched_barrier(0);
            if (kt < 14) asm volatile("s_waitcnt vmcnt(4)" ::: "memory");
            else         asm volatile("s_waitcnt vmcnt(0)" ::: "memory");
            __builtin_amdgcn_sched_barrier(0);
            __builtin_amdgcn_s_barrier();
            __builtin_amdgcn_sched_barrier(0);
        }
    }
#undef LOADED
#undef STAGE_B
#undef GELU_A

    // ---- epilogue via per-wave LDS pad: 16 rows x 132 f32 (8448 B each, 8 waves = 67.6KB)
    asm volatile("s_waitcnt lgkmcnt(0)" ::: "memory");
    __builtin_amdgcn_sched_barrier(0);
    __builtin_amdgcn_s_barrier();          // all waves done reading As/Bs -> LDS reusable
    __builtin_amdgcn_sched_barrier(0);

    char* ep = lds + w * 8448;
    int l31 = lane & 31, lh = lane >> 5;
#pragma unroll
    for (int mi = 0; mi < 4; mi++) {
        // scatter acc (col-per-lane) into row-major pad; banks: <=2-way (free)
#pragma unroll
        for (int ni = 0; ni < 8; ni++) {
            int c = ni * 16 + l15;
#pragma unroll
            for (int q = 0; q < 4; q++)
                *(float*)(ep + ((lg * 4 + q) * 132 + c) * 4) = acc[mi][ni][q];
        }
        asm volatile("s_waitcnt lgkmcnt(0)" ::: "memory");
        __builtin_amdgcn_sched_barrier(0);
        // read back contiguous, store 16B/lane: 1KB contiguous per instr
#pragma unroll
        for (int it = 0; it < 8; it++) {
            int r = it * 2 + lh;
            f32x4 v = *(const f32x4*)(ep + (r * 132 + l31 * 4) * 4);
            size_t row = m0 + wm * 64 + mi * 16 + r;
            float* o = out + row * 1024 + n0 + wn * 128 + l31 * 4;
            __builtin_nontemporal_store(v, (f32x4*)o);
        }
        asm volatile("s_waitcnt lgkmcnt(0)" ::: "memory");   // reads done before next mi overwrite
        __builtin_amdgcn_sched_barrier(0);
    }
}

extern "C" void kernel_launch(void* const* d_in, const int* in_sizes, int n_in,
                              void* d_out, int out_size, void* d_ws, size_t ws_size,
                              hipStream_t stream) {
    const float* enc = (const float*)d_in[0];   // (4,256,512)
    const float* dec = (const float*)d_in[1];   // (4,96,512)
    const float* W1  = (const float*)d_in[2];   // (1024,512)
    const float* b1  = (const float*)d_in[3];   // (512,)
    const float* W2  = (const float*)d_in[4];   // (512,1024)
    float* out = (float*)d_out;                 // (4,256,96,1024) f32

    char* ws = (char*)d_ws;
    float* he = (float*)(ws);                               // 1024x512 f32 (b1 folded)
    float* hd = (float*)(ws + 2097152);                     //  384x512 f32
    unsigned short* Wet = (unsigned short*)(ws + 2883584);  // 512x512 bf16 swz
    unsigned short* Wdt = (unsigned short*)(ws + 3407872);  // 512x512 bf16 swz
    unsigned short* W2t = (unsigned short*)(ws + 3932160);  // 1024x512 bf16 swz

    transpose_all<<<dim3(8, 16, 3), 256, 0, stream>>>(W1, W2, Wet, Wdt, W2t);
    gemm_small<<<dim3(11, 4), 256, 0, stream>>>(enc, dec, Wet, Wdt, b1, he, hd);
    joint_fused<<<dim3(768, 2), 512, 0, stream>>>(he, hd, W2t, out);
}

// Round 5
// 193.215 us; speedup vs baseline: 1.6077x; 1.0722x over previous
//
#include <hip/hip_runtime.h>
#include <hip/hip_bf16.h>

typedef __attribute__((ext_vector_type(8))) short short8;   // 8 bf16 = 4 VGPR (MFMA A/B frag)
typedef __attribute__((ext_vector_type(4))) float f32x4;    // MFMA C/D frag

__device__ __forceinline__ unsigned short f2bf(float f) {
    union { __hip_bfloat16 h; unsigned short u; } cv;
    cv.h = __float2bfloat16(f);   // RNE
    return cv.u;
}

// jax.nn.gelu(approximate=True): 0.5x(1+tanh(sqrt(2/pi)(x+0.044715x^3))) == x*e/(e+1), e=exp(2*inner)
__device__ __forceinline__ float gelu_t(float x) {
    float e = __expf(1.5957691216057308f * x * __builtin_fmaf(0.044715f, x * x, 1.0f));
    return x * (e / (e + 1.0f));
}

__device__ __forceinline__ void gload_lds16(const void* g, void* l) {
    __builtin_amdgcn_global_load_lds((const __attribute__((address_space(1))) unsigned int*)g,
                                     (__attribute__((address_space(3))) unsigned int*)l, 16, 0, 0);
}

// XOR swizzle key for 64B LDS rows: row r -> ((r>>1)&3)<<4 (conflicts==0 measured R3)
__device__ __forceinline__ int swzkey(int r) { return ((r >> 1) & 3) << 4; }

// ---------------------------------------------------------------------------
// Fused transpose + f32->bf16 + pre-swizzle for We, Wd, W2 (one launch). (verified R3/R4)
// ---------------------------------------------------------------------------
__global__ __launch_bounds__(256) void transpose_all(const float* __restrict__ W1,
                                                     const float* __restrict__ W2,
                                                     unsigned short* __restrict__ Wet,
                                                     unsigned short* __restrict__ Wdt,
                                                     unsigned short* __restrict__ W2t) {
    int z = blockIdx.z;
    if (z < 2 && blockIdx.y >= 8) return;      // We/Wd have N=512
    const float* in = (z == 0) ? W1 : (z == 1) ? (W1 + 512 * 512) : W2;
    unsigned short* out = (z == 0) ? Wet : (z == 1) ? Wdt : W2t;
    int N = (z == 2) ? 1024 : 512;

    __shared__ float tile[64][65];
    int k0 = blockIdx.x * 64, n0 = blockIdx.y * 64;
    int t = threadIdx.x;
    int c = t & 63, r0 = t >> 6;
#pragma unroll
    for (int i = 0; i < 16; i++) {
        int r = r0 + i * 4;
        tile[r][c] = in[(size_t)(k0 + r) * N + n0 + c];
    }
    __syncthreads();
    int kk = t & 15;
    int nl0 = t >> 4;
#pragma unroll
    for (int i = 0; i < 4; i++) {
        int nl = nl0 + i * 16;
        int n  = n0 + nl;
        unsigned short b0 = f2bf(tile[kk * 4 + 0][nl]);
        unsigned short b1 = f2bf(tile[kk * 4 + 1][nl]);
        unsigned short b2 = f2bf(tile[kk * 4 + 2][nl]);
        unsigned short b3 = f2bf(tile[kk * 4 + 3][nl]);
        uint2 v;
        v.x = (unsigned)b0 | ((unsigned)b1 << 16);
        v.y = (unsigned)b2 | ((unsigned)b3 << 16);
        int byte_in_chunk = kk * 8;
        int slice = byte_in_chunk & ~63;
        int off   = (byte_in_chunk & 63) ^ swzkey(n);
        size_t obyte = (size_t)n * 1024 + (size_t)k0 * 2 + slice + off;
        *(uint2*)((char*)out + obyte) = v;
    }
}

// ---------------------------------------------------------------------------
// he/hd GEMM (one launch): C[M][512] = A[M][512] @ Bt^T (+bias). (verified R3/R4)
// ---------------------------------------------------------------------------
__global__ __launch_bounds__(256, 2) void gemm_small(const float* __restrict__ enc,
                                                     const float* __restrict__ dec,
                                                     const unsigned short* __restrict__ Wet,
                                                     const unsigned short* __restrict__ Wdt,
                                                     const float* __restrict__ b1,
                                                     float* __restrict__ he,
                                                     float* __restrict__ hd) {
    bool isEnc = blockIdx.x < 8;
    const float* A = isEnc ? enc : dec;
    const unsigned short* Bt = isEnc ? Wet : Wdt;
    const float* bias = isEnc ? b1 : nullptr;
    float* C = isEnc ? he : hd;
    size_t m0 = (size_t)(isEnc ? blockIdx.x : blockIdx.x - 8) * 128;

    __shared__ alignas(16) unsigned short As[128 * 32];
    __shared__ alignas(16) unsigned short Bs[128 * 32];
    int t = threadIdx.x;
    int n0 = blockIdx.y * 128;
    int lane = t & 63, w = t >> 6;
    int wm = w >> 1, wn = w & 1;
    int rA = t >> 3, cg = t & 7;
    f32x4 acc[4][4] = {};

    for (int kt = 0; kt < 16; ++kt) {
        int k0 = kt * 32;
        __syncthreads();
#pragma unroll
        for (int p = 0; p < 4; p++) {
            int r = rA + p * 32;
            f32x4 v = *(const f32x4*)&A[(m0 + r) * 512 + k0 + cg * 4];
            uint2 pk;
            pk.x = (unsigned)f2bf(v.x) | ((unsigned)f2bf(v.y) << 16);
            pk.y = (unsigned)f2bf(v.z) | ((unsigned)f2bf(v.w) << 16);
            int off = (cg * 8) ^ swzkey(r);
            *(uint2*)((char*)As + r * 64 + off) = pk;
        }
#pragma unroll
        for (int j = 0; j < 2; j++) {
            int ibyte = w * 1024 + j * 4096;
            int lb = ibyte + lane * 16;
            int row = lb >> 6, colb = lb & 63;
            const char* src = (const char*)Bt + (size_t)(n0 + row) * 1024 + k0 * 2 + colb;
            gload_lds16(src, (char*)Bs + ibyte);
        }
        __syncthreads();
        short8 af[4], bf[4];
#pragma unroll
        for (int mi = 0; mi < 4; mi++) {
            int r = wm * 64 + mi * 16 + (lane & 15);
            int off = ((lane >> 4) * 16) ^ swzkey(r);
            af[mi] = *(const short8*)((const char*)As + r * 64 + off);
        }
#pragma unroll
        for (int ni = 0; ni < 4; ni++) {
            int n = wn * 64 + ni * 16 + (lane & 15);
            int off = ((lane >> 4) * 16) ^ swzkey(n);
            bf[ni] = *(const short8*)((const char*)Bs + n * 64 + off);
        }
#pragma unroll
        for (int mi = 0; mi < 4; mi++)
#pragma unroll
            for (int ni = 0; ni < 4; ni++)
                acc[mi][ni] = __builtin_amdgcn_mfma_f32_16x16x32_bf16(af[mi], bf[ni], acc[mi][ni], 0, 0, 0);
    }
#pragma unroll
    for (int mi = 0; mi < 4; mi++) {
        int row = wm * 64 + mi * 16 + ((lane >> 4) << 2);
#pragma unroll
        for (int ni = 0; ni < 4; ni++) {
            int col = n0 + wn * 64 + ni * 16 + (lane & 15);
            float bv = bias ? bias[col] : 0.0f;
#pragma unroll
            for (int q = 0; q < 4; q++)
                C[(m0 + row + q) * 512 + col] = acc[mi][ni][q] + bv;
        }
    }
}

// ---------------------------------------------------------------------------
// Fused joint: out[m][v] = gelu(he[t(m)]+hd[b,u(m)]) @ W2.
// BM=64 BN=512 BK=32, 512 thr (8 waves 2m x 4n, 32x128/wave), 16 K-steps.
// vs R4: LDS 80->72KB so 2 blocks/CU co-resident (one block's epilogue writes
// overlap the other's K-loop). Counted vmcnt(2) barriers (4 B-loads drained,
// 2 he/hd reg loads in flight). Epilogue via LDS pad -> 16B/lane NT stores.
// ---------------------------------------------------------------------------
__global__ __launch_bounds__(512, 4) void joint_fused(const float* __restrict__ he,
                                                      const float* __restrict__ hd,
                                                      const unsigned short* __restrict__ W2t,
                                                      float* __restrict__ out) {
    __shared__ alignas(16) char lds[73728];
    // carve: As[0]=0, As[1]=4096, Bs[0]=8192, Bs[1]=40960   (A 4KB x2, B 32KB x2)
    int t = threadIdx.x;
    int lane = t & 63, w = t >> 6;
    int wm = w >> 2, wn = w & 3;           // 2m x 4n, wave owns 32x128
    int bx = blockIdx.x;                   // 0..1535, XCD-swizzle (1536 % 8 == 0 -> bijective)
    int mt = (bx & 7) * 192 + (bx >> 3);
    size_t m0 = (size_t)mt * 64;
    int n0 = blockIdx.y * 512;

    // ---- A-gen mapping (fixed per thread): row rA = t>>3, 4 k's at cg*4
    int rA = t >> 3, cg = t & 7;
    int mrow = (int)m0 + rA;
    int tI = mrow / 96;                    // b*256+t index into he (0..1023)
    int u  = mrow - tI * 96;
    const float* eP = he + (size_t)tI * 512 + cg * 4;
    const float* dP = hd + (size_t)((tI >> 8) * 96 + u) * 512 + cg * 4;
    int aoff = rA * 64 + ((cg * 8) ^ swzkey(rA));

    // ---- B staging: wave w covers Bs rows [w*64, w*64+64), 4 x 1KB insts
    const char* bSrc[4];
#pragma unroll
    for (int i = 0; i < 4; i++) {
        int row = w * 64 + i * 16 + (lane >> 2);
        bSrc[i] = (const char*)W2t + (size_t)(n0 + row) * 1024 + (lane & 3) * 16;
    }

    // ---- fragment byte offsets
    int l15 = lane & 15, lg = lane >> 4;
    int aOff[2], bOff[8];
#pragma unroll
    for (int mi = 0; mi < 2; mi++) {
        int r = wm * 32 + mi * 16 + l15;
        aOff[mi] = r * 64 + ((lg * 16) ^ swzkey(r));
    }
#pragma unroll
    for (int ni = 0; ni < 8; ni++) {
        int n = wn * 128 + ni * 16 + l15;
        bOff[ni] = 8192 + n * 64 + ((lg * 16) ^ swzkey(n));   // +Bs base
    }

    f32x4 acc[2][8] = {};
    f32x4 er[2], dr[2];                    // 2-slot rotation, static idx (unrolled)

#define LOADED(slot, kt)  do { \
        er[slot] = *(const f32x4*)(eP + (kt) * 32); \
        dr[slot] = *(const f32x4*)(dP + (kt) * 32); } while (0)

#define STAGE_B(buf, kt)  do { \
        _Pragma("unroll") \
        for (int i = 0; i < 4; i++) \
            gload_lds16(bSrc[i] + (kt) * 64, lds + 8192 + (buf) * 32768 + w * 4096 + i * 1024); } while (0)

#define GELU_A(buf, slot) do { \
        uint2 pk; \
        pk.x = (unsigned)f2bf(gelu_t(er[slot].x + dr[slot].x)) | \
               ((unsigned)f2bf(gelu_t(er[slot].y + dr[slot].y)) << 16); \
        pk.y = (unsigned)f2bf(gelu_t(er[slot].z + dr[slot].z)) | \
               ((unsigned)f2bf(gelu_t(er[slot].w + dr[slot].w)) << 16); \
        *(uint2*)(lds + (buf) * 4096 + aoff) = pk; } while (0)

    // ---- prologue: B(0) staged, regs tile0+tile1 in flight, A(0) written
    STAGE_B(0, 0);
    LOADED(0, 0);
    LOADED(1, 1);
    GELU_A(0, 0);                          // compiler-wait drains slot-0 regs (and B(0), older)
    asm volatile("s_waitcnt lgkmcnt(0)" ::: "memory");
    asm volatile("s_waitcnt vmcnt(2)" ::: "memory");   // B(0) landed; tile-1 regs may fly
    __builtin_amdgcn_sched_barrier(0);
    __builtin_amdgcn_s_barrier();
    __builtin_amdgcn_sched_barrier(0);

#pragma unroll
    for (int kt = 0; kt < 16; ++kt) {
        const int cur = kt & 1, nxt = cur ^ 1;
        // issue next-tile staging and next-next reg loads first (fly under compute)
        if (kt < 15) STAGE_B(nxt, kt + 1);
        if (kt < 14) LOADED(cur, kt + 2);                 // slot kt&1 free: consumed last step
        if (kt < 15) GELU_A(nxt, nxt);                    // A(kt+1) from regs slot (kt+1)&1
        // fragments + MFMA from cur
        short8 a[2];
#pragma unroll
        for (int mi = 0; mi < 2; mi++) a[mi] = *(const short8*)(lds + cur * 4096 + aOff[mi]);
        __builtin_amdgcn_s_setprio(1);
#pragma unroll
        for (int ni = 0; ni < 8; ni++) {
            short8 b = *(const short8*)(lds + cur * 32768 + bOff[ni]);
#pragma unroll
            for (int mi = 0; mi < 2; mi++)
                acc[mi][ni] = __builtin_amdgcn_mfma_f32_16x16x32_bf16(a[mi], b, acc[mi][ni], 0, 0, 0);
        }
        __builtin_amdgcn_s_setprio(0);
        if (kt < 15) {
            // own frag reads + A(nxt) ds_write done; B(nxt) landed; reg loads stay in flight
            asm volatile("s_waitcnt lgkmcnt(0)" ::: "memory");
            __builtin_amdgcn_sched_barrier(0);
            if (kt < 14) asm volatile("s_waitcnt vmcnt(2)" ::: "memory");
            else         asm volatile("s_waitcnt vmcnt(0)" ::: "memory");
            __builtin_amdgcn_sched_barrier(0);
            __builtin_amdgcn_s_barrier();
            __builtin_amdgcn_sched_barrier(0);
        }
    }
#undef LOADED
#undef STAGE_B
#undef GELU_A

    // ---- epilogue via per-wave LDS pad: 16 rows x 132 f32 (8448 B/wave, 67.6KB tot)
    asm volatile("s_waitcnt lgkmcnt(0)" ::: "memory");
    __builtin_amdgcn_sched_barrier(0);
    __builtin_amdgcn_s_barrier();          // all waves done reading As/Bs -> LDS reusable
    __builtin_amdgcn_sched_barrier(0);

    char* ep = lds + w * 8448;
    int l31 = lane & 31, lh = lane >> 5;
#pragma unroll
    for (int mi = 0; mi < 2; mi++) {
        // scatter acc (col-per-lane) into row-major pad; <=2-way banks (free)
#pragma unroll
        for (int ni = 0; ni < 8; ni++) {
            int c = ni * 16 + l15;
#pragma unroll
            for (int q = 0; q < 4; q++)
                *(float*)(ep + ((lg * 4 + q) * 132 + c) * 4) = acc[mi][ni][q];
        }
        asm volatile("s_waitcnt lgkmcnt(0)" ::: "memory");
        __builtin_amdgcn_sched_barrier(0);
        // read back contiguous, store 16B/lane: 1KB contiguous per instr
#pragma unroll
        for (int it = 0; it < 8; it++) {
            int r = it * 2 + lh;
            f32x4 v = *(const f32x4*)(ep + (r * 132 + l31 * 4) * 4);
            size_t row = m0 + wm * 32 + mi * 16 + r;
            float* o = out + row * 1024 + n0 + wn * 128 + l31 * 4;
            __builtin_nontemporal_store(v, (f32x4*)o);
        }
        asm volatile("s_waitcnt lgkmcnt(0)" ::: "memory");   // reads done before next mi overwrite
        __builtin_amdgcn_sched_barrier(0);
    }
}

extern "C" void kernel_launch(void* const* d_in, const int* in_sizes, int n_in,
                              void* d_out, int out_size, void* d_ws, size_t ws_size,
                              hipStream_t stream) {
    const float* enc = (const float*)d_in[0];   // (4,256,512)
    const float* dec = (const float*)d_in[1];   // (4,96,512)
    const float* W1  = (const float*)d_in[2];   // (1024,512)
    const float* b1  = (const float*)d_in[3];   // (512,)
    const float* W2  = (const float*)d_in[4];   // (512,1024)
    float* out = (float*)d_out;                 // (4,256,96,1024) f32

    char* ws = (char*)d_ws;
    float* he = (float*)(ws);                               // 1024x512 f32 (b1 folded)
    float* hd = (float*)(ws + 2097152);                     //  384x512 f32
    unsigned short* Wet = (unsigned short*)(ws + 2883584);  // 512x512 bf16 swz
    unsigned short* Wdt = (unsigned short*)(ws + 3407872);  // 512x512 bf16 swz
    unsigned short* W2t = (unsigned short*)(ws + 3932160);  // 1024x512 bf16 swz

    transpose_all<<<dim3(8, 16, 3), 256, 0, stream>>>(W1, W2, Wet, Wdt, W2t);
    gemm_small<<<dim3(11, 4), 256, 0, stream>>>(enc, dec, Wet, Wdt, b1, he, hd);
    joint_fused<<<dim3(1536, 2), 512, 0, stream>>>(he, hd, W2t, out);
}